// Round 4
// baseline (417.749 us; speedup 1.0000x reference)
//
#include <hip/hip_runtime.h>
#include <hip/hip_bf16.h>
#include <math.h>

#define B_TOTAL 262144
#define D 16
#define CTX 128
#define H 192
#define KX 192       // extended layer-1 K: [y16,t1,0*15 | h128 | ylo16,tlo1,0*15]
#define M 32         // rows per block
#define BLOCK 256

typedef __attribute__((ext_vector_type(8))) short bf16x8;
typedef __attribute__((ext_vector_type(4))) float f32x4;

#define MFMA(a, b, c) __builtin_amdgcn_mfma_f32_16x16x32_bf16((a), (b), (c), 0, 0, 0)

__device__ __forceinline__ unsigned short f2bf_rne(float f) {
    unsigned u = __builtin_bit_cast(unsigned, f);
    u += 0x7FFFu + ((u >> 16) & 1u);
    return (unsigned short)(u >> 16);
}
// truncation split: hi = trunc-bf16(v) (exact), lo = RNE(v - hi) (v-hi exact in f32)
__device__ __forceinline__ void split2(float v, unsigned short& hi, unsigned short& lo) {
    unsigned u = __builtin_bit_cast(unsigned, v);
    hi = (unsigned short)(u >> 16);
    float hf = __builtin_bit_cast(float, u & 0xFFFF0000u);
    lo = f2bf_rne(v - hf);
}
// phi = 0.5(1+erf(x/sqrt2)) via A&S 7.1.25 3-term (|eps|<=2.5e-5), exp shared with pdf
__device__ __forceinline__ void gelu_pair(float x, float& a, float& gp) {
    float e    = __expf(-0.5f * x * x);                  // e^{-x^2/2}
    float az   = fabsf(x) * 0.70710678118654752f;
    float t    = __builtin_amdgcn_rcpf(fmaf(0.47047f, az, 1.0f));
    float p    = t * fmaf(t, fmaf(t, 0.7478556f, -0.0958798f), 0.3480242f);
    float erfv = __builtin_copysignf(fmaf(-p, e, 1.0f), x);
    float phi  = fmaf(0.5f, erfv, 0.5f);
    gp = fmaf(0.39894228040143268f * x, e, phi);          // phi + x*pdf
    a  = x * phi;
}

// ---------- pre-kernel: weights -> [N][K] bf16 in d_ws ----------
// Wt1x: [192][192] @0      (k' map: 0-15 y | 16 t | 17-31 zero | 32-159 h rows |
//                           160-175 y dup | 176 t dup | 177-191 zero)
// Wt2:  [192][192] @36864 ; Wt3: [16][192] @73728
__global__ void prep_weights(const float* __restrict__ W1,
                             const float* __restrict__ W2,
                             const float* __restrict__ W3,
                             unsigned short* __restrict__ wt)
{
    int i = blockIdx.x * 256 + threadIdx.x;
    if (i < H * KX) {
        int n = i / KX, kp = i % KX;
        float v = 0.0f;
        if (kp < 16)                       v = W1[kp * H + n];
        else if (kp == 16)                 v = W1[144 * H + n];
        else if (kp >= 32 && kp < 160)     v = W1[(kp - 16) * H + n];
        else if (kp >= 160 && kp < 176)    v = W1[(kp - 160) * H + n];
        else if (kp == 176)                v = W1[144 * H + n];
        wt[i] = f2bf_rne(v);
        return;
    }
    i -= H * KX;
    if (i < H * H) {
        int n = i / H, k = i % H;
        wt[36864 + i] = f2bf_rne(W2[k * H + n]);
        return;
    }
    i -= H * H;
    if (i < D * H) {
        int n = i / H, k = i % H;
        wt[73728 + i] = f2bf_rne(W3[k * D + n]);
    }
}

// ---------- main kernel ----------
__global__ __launch_bounds__(BLOCK, 5) void odefunc_mfma(
    const float* __restrict__ t_ptr,
    const float* __restrict__ y,
    const float* __restrict__ h,
    const float* __restrict__ eps,
    const float* __restrict__ b1,
    const float* __restrict__ b2,
    const float* __restrict__ b3,
    const unsigned short* __restrict__ wt,
    float* __restrict__ out_f,
    float* __restrict__ out_dlogp,
    float* __restrict__ out_dh)
{
    // LDS 30208 B -> 5 blocks/CU.  region0 = Xh(12800)+Tc(4608); A overlays Xh; U @17408.
    __shared__ __align__(16) unsigned char smem[30208];
    unsigned short (*Xh)[200] = (unsigned short (*)[200])smem;
    unsigned short (*Tc)[72]  = (unsigned short (*)[72])(smem + 12800);
    unsigned short (*A)[200]  = (unsigned short (*)[200])smem;          // post-b2 overlay
    unsigned short (*U)[200]  = (unsigned short (*)[200])(smem + 17408);

    const int tid  = threadIdx.x;
    const int lane = tid & 63;
    const int wv   = tid >> 6;
    const int quad = lane >> 4;
    const int l16  = lane & 15;
    const size_t r0 = (size_t)blockIdx.x * M;

    const unsigned short* Wt1 = wt;
    const unsigned short* Wt2 = wt + 36864;
    const unsigned short* Wt3 = wt + 73728;

    // ------- zero dh slice -------
    {
        float4 z4 = {0.f, 0.f, 0.f, 0.f};
        #pragma unroll
        for (int i = 0; i < 4; ++i) {
            int idx = tid + i * BLOCK;            // 1024 float4 = 32 rows x 32
            int r = idx >> 5, c4 = (idx & 31) * 4;
            *(float4*)(out_dh + (r0 + r) * CTX + c4) = z4;
        }
    }

    // ------------- stage inputs -------------
    {   // y -> Xh cols 0-15 / 160-175 ; eps -> Tc cols 0-15 / 32-47
        int task = tid >> 7, idx = tid & 127;
        int r = idx >> 2, d4 = (idx & 3) * 4;
        const float* src = task ? eps : y;
        float4 v = *(const float4*)(src + (r0 + r) * D + d4);
        ushort4 hi, lo;
        split2(v.x, hi.x, lo.x); split2(v.y, hi.y, lo.y);
        split2(v.z, hi.z, lo.z); split2(v.w, hi.w, lo.w);
        if (task == 0) { *(ushort4*)&Xh[r][d4] = hi; *(ushort4*)&Xh[r][160 + d4] = lo; }
        else           { *(ushort4*)&Tc[r][d4] = hi; *(ushort4*)&Tc[r][32 + d4] = lo; }
    }
    if (tid < M) {      // t cols + zero pads
        int r = tid;
        float tv = t_ptr[0];
        unsigned short thi, tlo;
        split2(tv, thi, tlo);
        ushort4 z4 = {0, 0, 0, 0};
        ushort4 t4 = {thi, 0, 0, 0};
        ushort4 l4 = {tlo, 0, 0, 0};
        *(ushort4*)&Xh[r][16]  = t4; *(ushort4*)&Xh[r][20]  = z4;
        *(ushort4*)&Xh[r][24]  = z4; *(ushort4*)&Xh[r][28]  = z4;
        *(ushort4*)&Xh[r][176] = l4; *(ushort4*)&Xh[r][180] = z4;
        *(ushort4*)&Xh[r][184] = z4; *(ushort4*)&Xh[r][188] = z4;
        *(ushort4*)&Tc[r][16]  = z4; *(ushort4*)&Tc[r][20]  = z4;
        *(ushort4*)&Tc[r][24]  = z4; *(ushort4*)&Tc[r][28]  = z4;
        *(ushort4*)&Tc[r][48]  = z4; *(ushort4*)&Tc[r][52]  = z4;
        *(ushort4*)&Tc[r][56]  = z4; *(ushort4*)&Tc[r][60]  = z4;
    }
    #pragma unroll
    for (int i = 0; i < 4; ++i) {   // h: single bf16 plane -> Xh cols 32-159
        int idx = tid + i * BLOCK;
        int r = idx >> 5, c4 = (idx & 31) * 4;
        float4 v = *(const float4*)(h + (r0 + r) * CTX + c4);
        ushort4 hv = { f2bf_rne(v.x), f2bf_rne(v.y), f2bf_rne(v.z), f2bf_rne(v.w) };
        *(ushort4*)&Xh[r][32 + c4] = hv;
    }
    __syncthreads();                                   // b1

    const f32x4 zf = {0.f, 0.f, 0.f, 0.f};

    // ------------- layer 1 -------------
    f32x4 z[2][3], u[2][3];
    #pragma unroll
    for (int rt = 0; rt < 2; ++rt)
        #pragma unroll
        for (int j = 0; j < 3; ++j) { z[rt][j] = zf; u[rt][j] = zf; }

    bf16x8 w1f[3][6];
    #pragma unroll
    for (int j = 0; j < 3; ++j) {
        int n = (wv * 3 + j) * 16 + l16;
        #pragma unroll
        for (int kc = 0; kc < 6; ++kc)
            w1f[j][kc] = *(const bf16x8*)(Wt1 + n * KX + kc * 32 + quad * 8);
    }
    #pragma unroll
    for (int kc = 0; kc < 6; ++kc)
        #pragma unroll
        for (int rt = 0; rt < 2; ++rt) {
            bf16x8 ah = *(const bf16x8*)&Xh[rt * 16 + l16][kc * 32 + quad * 8];
            #pragma unroll
            for (int j = 0; j < 3; ++j) z[rt][j] = MFMA(ah, w1f[j][kc], z[rt][j]);
        }
    #pragma unroll
    for (int rt = 0; rt < 2; ++rt) {   // tangent: chunk0 (eps_hi) + chunk5 (eps_lo)
        int m = rt * 16 + l16;
        bf16x8 th = *(const bf16x8*)&Tc[m][quad * 8];
        bf16x8 tl = *(const bf16x8*)&Tc[m][32 + quad * 8];
        #pragma unroll
        for (int j = 0; j < 3; ++j) {
            u[rt][j] = MFMA(th, w1f[j][0], u[rt][j]);
            u[rt][j] = MFMA(tl, w1f[j][5], u[rt][j]);
        }
    }
    __syncthreads();                                   // b2: X/T reads done, A may overlay

    // epilogue 1
    #pragma unroll
    for (int j = 0; j < 3; ++j) {
        int n = (wv * 3 + j) * 16 + l16;
        float bb = b1[n];
        #pragma unroll
        for (int rt = 0; rt < 2; ++rt)
            #pragma unroll
            for (int rg = 0; rg < 4; ++rg) {
                int m = rt * 16 + quad * 4 + rg;
                float x = z[rt][j][rg] + bb;
                float a, gp; gelu_pair(x, a, gp);
                A[m][n] = f2bf_rne(a);
                U[m][n] = f2bf_rne(u[rt][j][rg] * gp);
            }
    }
    __syncthreads();                                   // b3

    // ------------- layer 2 -------------
    f32x4 z2[2][3], u2[2][3];
    #pragma unroll
    for (int rt = 0; rt < 2; ++rt)
        #pragma unroll
        for (int j = 0; j < 3; ++j) { z2[rt][j] = zf; u2[rt][j] = zf; }

    bf16x8 w2f[3][6];
    #pragma unroll
    for (int j = 0; j < 3; ++j) {
        int n = (wv * 3 + j) * 16 + l16;
        #pragma unroll
        for (int kc = 0; kc < 6; ++kc)
            w2f[j][kc] = *(const bf16x8*)(Wt2 + n * H + kc * 32 + quad * 8);
    }
    #pragma unroll
    for (int kc = 0; kc < 6; ++kc)
        #pragma unroll
        for (int rt = 0; rt < 2; ++rt) {
            int m = rt * 16 + l16, o = kc * 32 + quad * 8;
            bf16x8 av = *(const bf16x8*)&A[m][o];
            bf16x8 uv = *(const bf16x8*)&U[m][o];
            #pragma unroll
            for (int j = 0; j < 3; ++j) {
                z2[rt][j] = MFMA(av, w2f[j][kc], z2[rt][j]);
                u2[rt][j] = MFMA(uv, w2f[j][kc], u2[rt][j]);
            }
        }
    __syncthreads();                                   // b4: A/U reads done

    // epilogue 2 (in place)
    #pragma unroll
    for (int j = 0; j < 3; ++j) {
        int n = (wv * 3 + j) * 16 + l16;
        float bb = b2[n];
        #pragma unroll
        for (int rt = 0; rt < 2; ++rt)
            #pragma unroll
            for (int rg = 0; rg < 4; ++rg) {
                int m = rt * 16 + quad * 4 + rg;
                float x = z2[rt][j][rg] + bb;
                float a, gp; gelu_pair(x, a, gp);
                A[m][n] = f2bf_rne(a);
                U[m][n] = f2bf_rne(u2[rt][j][rg] * gp);
            }
    }
    __syncthreads();                                   // b5

    // ------------- layer 3 + outputs -------------
    // wave 0: rows 0-15 value | wave 1: rows 0-15 tangent | waves 2/3: rows 16-31
    {
        const int strm = wv & 1, rt = wv >> 1;
        const unsigned short (*P)[200] = strm ? U : A;

        bf16x8 w3f[6];
        #pragma unroll
        for (int kc = 0; kc < 6; ++kc)
            w3f[kc] = *(const bf16x8*)(Wt3 + l16 * H + kc * 32 + quad * 8);

        f32x4 acc = zf;
        #pragma unroll
        for (int kc = 0; kc < 6; ++kc) {
            bf16x8 xv = *(const bf16x8*)&P[rt * 16 + l16][kc * 32 + quad * 8];
            acc = MFMA(xv, w3f[kc], acc);
        }

        if (strm == 0) {
            float bb = b3[l16];
            #pragma unroll
            for (int rg = 0; rg < 4; ++rg) {
                int m = rt * 16 + quad * 4 + rg;
                out_f[(r0 + m) * D + l16] = acc[rg] + bb;
            }
        } else {
            float pr[4];
            #pragma unroll
            for (int rg = 0; rg < 4; ++rg) {
                int m = rt * 16 + quad * 4 + rg;
                pr[rg] = acc[rg] * eps[(r0 + m) * D + l16];
            }
            #pragma unroll
            for (int sh = 1; sh < 16; sh <<= 1)
                #pragma unroll
                for (int rg = 0; rg < 4; ++rg)
                    pr[rg] += __shfl_xor(pr[rg], sh, 64);
            if (l16 == 0)
                #pragma unroll
                for (int rg = 0; rg < 4; ++rg)
                    out_dlogp[r0 + rt * 16 + quad * 4 + rg] = -pr[rg];
        }
    }
}

extern "C" void kernel_launch(void* const* d_in, const int* in_sizes, int n_in,
                              void* d_out, int out_size, void* d_ws, size_t ws_size,
                              hipStream_t stream)
{
    const float* t   = (const float*)d_in[0];
    const float* y   = (const float*)d_in[1];
    const float* h   = (const float*)d_in[3];
    const float* eps = (const float*)d_in[4];
    const float* W1  = (const float*)d_in[5];
    const float* b1  = (const float*)d_in[6];
    const float* W2  = (const float*)d_in[7];
    const float* b2  = (const float*)d_in[8];
    const float* W3  = (const float*)d_in[9];
    const float* b3  = (const float*)d_in[10];

    float* out       = (float*)d_out;
    float* out_f     = out;
    float* out_dlogp = out + (size_t)B_TOTAL * D;
    float* out_dh    = out + (size_t)B_TOTAL * (D + 1);

    unsigned short* wt = (unsigned short*)d_ws;

    int prep_elems = H * KX + H * H + D * H;   // 76800
    prep_weights<<<(prep_elems + 255) / 256, 256, 0, stream>>>(W1, W2, W3, wt);

    odefunc_mfma<<<B_TOTAL / M, BLOCK, 0, stream>>>(
        t, y, h, eps, b1, b2, b3, wt, out_f, out_dlogp, out_dh);
}